// Round 2
// baseline (21.139 us; speedup 1.0000x reference)
//
#include <hip/hip_runtime.h>

// 8-qubit effective circuit (qubits 8..10 of the reference stay |0>).
// Physical layout: batch element -> one wave; physical index i in [0,256):
//   i = lane*4 + j (lane = i[7:2], reg j = i[1:0]); i bit b <-> qubit 7-b.
// CNOT ring layers are linear maps over GF(2) on the index bits -> tracked as
// a relabeling matrix T (T_m = P^m), never executed. RY on logical bit b at
// layer m becomes an XOR-butterfly with physical mask M = T_m^{-1} e_b and
// sign parity(row_b(T_m) & i). Commuting RY gates are merged in pairs into
// 4-point butterflies: one dependent cross-lane stage per pair.

namespace {

struct M8 { unsigned r[8]; };  // r[b] = row b: bit k set => output bit b depends on input bit k

constexpr M8 kI{{0x01,0x02,0x04,0x08,0x10,0x20,0x40,0x80}};
// Ring q=0..7 (c=7-q, t=6-q mod): sequential b6^=b7, b5^=b6, ..., b0^=b1, b7^=b0
constexpr M8 kP{{0xFF,0xFE,0xFC,0xF8,0xF0,0xE0,0xC0,0x7F}};
// Inverse (ops reversed): b7^=b0, b0^=b1, ..., b6^=b7
constexpr M8 kQ{{0x03,0x06,0x0C,0x18,0x30,0x60,0xC1,0x81}};

constexpr M8 mul(const M8& A, const M8& B) {  // C(x) = A(B(x))
  M8 C{{0,0,0,0,0,0,0,0}};
  for (int j = 0; j < 8; ++j) {
    unsigned by = 0;
    for (int b = 0; b < 8; ++b) by |= ((B.r[b] >> j) & 1u) << b;
    for (int b = 0; b < 8; ++b) {
      unsigned v = A.r[b] & by;
      v ^= v >> 4; v ^= v >> 2; v ^= v >> 1;
      C.r[b] |= (v & 1u) << j;
    }
  }
  return C;
}

constexpr bool eqI(const M8& A) {
  bool e = true;
  for (int b = 0; b < 8; ++b) e = e && (A.r[b] == (1u << b));
  return e;
}

struct Tables { unsigned Mm[21][8]; unsigned Rr[21][8]; bool ok; };

constexpr Tables build() {
  Tables t{};
  M8 T = kI, Ti = kI;
  bool ok = eqI(mul(kP, kQ)) && eqI(mul(kQ, kP));
  for (int m = 0; m <= 20; ++m) {
    ok = ok && eqI(mul(T, Ti));
    for (int b = 0; b < 8; ++b) {
      unsigned mm = 0;
      for (int k = 0; k < 8; ++k) mm |= ((Ti.r[k] >> b) & 1u) << k;  // column b of T^-1
      t.Mm[m][b] = mm;
      t.Rr[m][b] = T.r[b];
    }
    T = mul(kP, T);
    Ti = mul(Ti, kQ);
  }
  t.ok = ok;
  return t;
}

constexpr Tables kT = build();
static_assert(kT.ok, "GF(2) inverse tracking failed");
static_assert(kT.Mm[0][5] == 0x20 && kT.Rr[0][3] == 0x08, "layer-0 must be identity");

// Partner value at physical index i ^ M, for register slot J.
template<unsigned M, int J>
__device__ __forceinline__ float part(const float (&s)[4]) {
  constexpr int jj = J ^ (int)(M & 3u);
  constexpr int lm = (int)(M >> 2);
  float v = s[jj];
  if constexpr (lm != 0) v = __shfl_xor(v, lm);
  return v;
}

// Merged pair of RY gates on logical bits bA=2*st+1, bB=2*st at layer m.
// out = cAcB*in + sAcB*sigA*in[^MA] + cAsB*sigB*in[^MB] + sAsB*sigA*sigB*in[^MA^MB]
template<int m, int st>
__device__ __forceinline__ void stage(int lane, const float4* __restrict__ ct4, float (&s)[4]) {
  constexpr int bA = 2 * st + 1, bB = 2 * st;
  constexpr unsigned MA = kT.Mm[m][bA];
  constexpr unsigned MB = kT.Mm[m][bB];
  constexpr unsigned MC = MA ^ MB;
  constexpr unsigned RA = kT.Rr[m][bA];
  constexpr unsigned RB = kT.Rr[m][bB];

  const float4 k = ct4[m * 4 + st];  // {cAcB, sAcB, cAsB, sAsB}
  const int sa = (__popc((int)(RA >> 2) & lane) & 1) << 31;
  const int sb = (__popc((int)(RB >> 2) & lane) & 1) << 31;

  float A[4] = { part<MA,0>(s), part<MA,1>(s), part<MA,2>(s), part<MA,3>(s) };
  float B[4] = { part<MB,0>(s), part<MB,1>(s), part<MB,2>(s), part<MB,3>(s) };
  float C[4] = { part<MC,0>(s), part<MC,1>(s), part<MC,2>(s), part<MC,3>(s) };

  float ns[4];
  #pragma unroll
  for (int j = 0; j < 4; ++j) {
    const int ka = ((__popc((int)(RA & 3u) & j) & 1) << 31) ^ sa;
    const int kb = ((__popc((int)(RB & 3u) & j) & 1) << 31) ^ sb;
    const float wa = __int_as_float(__float_as_int(k.y) ^ ka);
    const float wb = __int_as_float(__float_as_int(k.z) ^ kb);
    const float wc = __int_as_float(__float_as_int(k.w) ^ ka ^ kb);
    ns[j] = k.x * s[j] + wa * A[j] + wb * B[j] + wc * C[j];
  }
  s[0] = ns[0]; s[1] = ns[1]; s[2] = ns[2]; s[3] = ns[3];
}

template<int m>
__device__ __forceinline__ void run_layers(int lane, const float4* __restrict__ ct4, float (&s)[4]) {
  if constexpr (m <= 20) {
    stage<m, 0>(lane, ct4, s);
    stage<m, 1>(lane, ct4, s);
    stage<m, 2>(lane, ct4, s);
    stage<m, 3>(lane, ct4, s);
    run_layers<m + 1>(lane, ct4, s);
  }
}

}  // namespace

__global__ __launch_bounds__(256) void qae_kernel(const float* __restrict__ x,
                                                  const float* __restrict__ theta,
                                                  float* __restrict__ out) {
  __shared__ float4 ct4[84];  // 21 layers x 4 gate-pairs
  const int t = threadIdx.x;
  if (t < 84) {
    const int m = t >> 2, st = t & 3;
    const int qa = 6 - 2 * st;  // qubit of gate bA = 2*st+1 (b = 7-q)
    const int qb = 7 - 2 * st;  // qubit of gate bB = 2*st
    float sA, cA, sB, cB;
    sincosf(theta[m * 8 + qa] * 0.5f, &sA, &cA);
    sincosf(theta[m * 8 + qb] * 0.5f, &sB, &cB);
    ct4[t] = make_float4(cA * cB, sA * cB, cA * sB, sA * sB);
  }
  __syncthreads();

  const int lane = t & 63;
  const int b = blockIdx.x * 4 + (t >> 6);

  const float4 xv = *reinterpret_cast<const float4*>(x + (size_t)b * 256 + lane * 4);
  float s[4] = { xv.x, xv.y, xv.z, xv.w };

  run_layers<0>(lane, ct4, s);

  // B = logical bits 0..2 of T_20(i): parity rows
  constexpr unsigned R0 = kT.Rr[20][0], R1 = kT.Rr[20][1], R2 = kT.Rr[20][2];
  const int q0 = __popc((int)(R0 >> 2) & lane) & 1;
  const int q1 = __popc((int)(R1 >> 2) & lane) & 1;
  const int q2 = __popc((int)(R2 >> 2) & lane) & 1;

  float acc[8];
  #pragma unroll
  for (int B = 0; B < 8; ++B) acc[B] = 0.f;
  #pragma unroll
  for (int j = 0; j < 4; ++j) {
    const int bj = (q0 ^ (__popc((int)(R0 & 3u) & j) & 1))
                 | ((q1 ^ (__popc((int)(R1 & 3u) & j) & 1)) << 1)
                 | ((q2 ^ (__popc((int)(R2 & 3u) & j) & 1)) << 2);
    const float pj = s[j] * s[j];
    #pragma unroll
    for (int B = 0; B < 8; ++B) acc[B] += (bj == B) ? pj : 0.f;
  }
  #pragma unroll
  for (int mm = 1; mm < 64; mm <<= 1) {
    #pragma unroll
    for (int B = 0; B < 8; ++B) acc[B] += __shfl_xor(acc[B], mm);
  }
  if (lane == 0) {
    float4* o = reinterpret_cast<float4*>(out + (size_t)b * 8);
    o[0] = make_float4(acc[0], acc[1], acc[2], acc[3]);
    o[1] = make_float4(acc[4], acc[5], acc[6], acc[7]);
  }
}

extern "C" void kernel_launch(void* const* d_in, const int* in_sizes, int n_in,
                              void* d_out, int out_size, void* d_ws, size_t ws_size,
                              hipStream_t stream) {
  const float* x = (const float*)d_in[0];      // [1024, 256]
  const float* theta = (const float*)d_in[1];  // [168]
  float* out = (float*)d_out;                  // [1024, 8]
  qae_kernel<<<256, 256, 0, stream>>>(x, theta, out);
}